// Round 3
// baseline (293.744 us; speedup 1.0000x reference)
//
#include <hip/hip_runtime.h>
#include <hip/hip_bf16.h>
#include <math.h>

typedef short bf16x8 __attribute__((ext_vector_type(8)));
typedef float f32x4 __attribute__((ext_vector_type(4)));

#define MFMA16x16(a, b, c) __builtin_amdgcn_mfma_f32_16x16x32_bf16(a, b, c, 0, 0, 0)

__device__ __forceinline__ float silu_f(float v) { return v / (1.0f + __expf(-v)); }
// XOR swizzle for [row][128B] LDS tiles
__device__ __forceinline__ int swz128(int b) { return b ^ (((b >> 7) & 7) << 4); }

__device__ __forceinline__ unsigned short f2bf(float f) {  // RNE f32->bf16
  union { float f; unsigned u; } x; x.f = f;
  unsigned r = x.u + 0x7fffu + ((x.u >> 16) & 1u);
  return (unsigned short)(r >> 16);
}
__device__ __forceinline__ float bf2f(unsigned short h) {
  union { unsigned u; float f; } x; x.u = ((unsigned)h) << 16;
  return x.f;
}

__device__ __forceinline__ void gload_lds16(const void* g, void* l) {
  __builtin_amdgcn_global_load_lds((__attribute__((address_space(1))) unsigned int*)g,
                                   (__attribute__((address_space(3))) unsigned int*)l,
                                   16, 0, 0);
}

// ---------- offsets decode + balanced tile list (desc by work) ----------
__global__ void k_prep(const int* __restrict__ raw, int Bp1, int* __restrict__ offs,
                       int* __restrict__ tiles, int qtmax) {
  int t = threadIdx.x;
  bool is64 = (raw[3] == 0);
  if (t < Bp1) offs[t] = is64 ? raw[2 * t] : raw[t];
  __syncthreads();
  if (t == 0) {
    int B = Bp1 - 1;
    int cnt = 0;
    for (int qt = qtmax - 1; qt >= 0; --qt)      // longest units first
      for (int b = 0; b < B; ++b) {
        int len = offs[b + 1] - offs[b];
        int nt = (len + 31) >> 5;
        if (qt < nt) tiles[1 + cnt++] = (b << 16) | qt;
      }
    tiles[0] = cnt * 8;  // wave-unit count (x8 heads)
  }
}

// ---------- uvqk (512x2048 f32) -> uvqkT (2048x512 bf16), transposed ----------
__global__ __launch_bounds__(256) void k_conv_uvqkT(const float* __restrict__ uvqk,
                                                    unsigned short* __restrict__ uvqkT) {
  __shared__ float tile[32][33];
  int n0 = blockIdx.x * 32, k0 = blockIdx.y * 32;
  int tx = threadIdx.x & 31;
  int ty = threadIdx.x >> 5;
#pragma unroll
  for (int i = 0; i < 4; ++i)
    tile[ty + 8 * i][tx] = uvqk[(size_t)(k0 + ty + 8 * i) * 2048 + n0 + tx];
  __syncthreads();
#pragma unroll
  for (int i = 0; i < 4; ++i) {
    int nn = ty + 8 * i;
    uvqkT[(size_t)(n0 + nn) * 512 + k0 + tx] = f2bf(tile[tx][nn]);
  }
}

__global__ __launch_bounds__(256) void k_conv_bf16(const float* __restrict__ in,
                                                   unsigned short* __restrict__ out, int n) {
  int i = blockIdx.x * 256 + threadIdx.x;
  if (i < n) out[i] = f2bf(in[i]);
}

// ---------- LayerNorm(x) -> bf16, one wave per 512-row ----------
__global__ __launch_bounds__(256) void k_ln_x(const float* __restrict__ x,
                                              unsigned short* __restrict__ normed, int T) {
  int lane = threadIdx.x & 63, wid = threadIdx.x >> 6;
  int row = blockIdx.x * 4 + wid;
  if (row >= T) return;
  const float4* xr = (const float4*)(x + (size_t)row * 512);
  float4 a = xr[lane * 2], b = xr[lane * 2 + 1];
  float s = a.x + a.y + a.z + a.w + b.x + b.y + b.z + b.w;
  float s2 = a.x * a.x + a.y * a.y + a.z * a.z + a.w * a.w +
             b.x * b.x + b.y * b.y + b.z * b.z + b.w * b.w;
#pragma unroll
  for (int m = 1; m < 64; m <<= 1) { s += __shfl_xor(s, m); s2 += __shfl_xor(s2, m); }
  float mean = s * (1.0f / 512.0f);
  float var = s2 * (1.0f / 512.0f) - mean * mean;
  float rstd = rsqrtf(var + 1e-6f);
  float v[8] = {a.x, a.y, a.z, a.w, b.x, b.y, b.z, b.w};
  unsigned short o[8];
#pragma unroll
  for (int j = 0; j < 8; ++j) o[j] = f2bf((v[j] - mean) * rstd);
  *(uint4*)(normed + (size_t)row * 512 + lane * 8) = *(uint4*)o;
}

// ---------- o_input = u * LayerNorm(attn_bf16) -> bf16 ----------
__global__ __launch_bounds__(256) void k_ln_mul_u(const unsigned short* __restrict__ attnb,
                                                  const unsigned short* __restrict__ mm,
                                                  unsigned short* __restrict__ oin, int T) {
  int lane = threadIdx.x & 63, wid = threadIdx.x >> 6;
  int row = blockIdx.x * 4 + wid;
  if (row >= T) return;
  uint4 av = *(const uint4*)(attnb + (size_t)row * 512 + lane * 8);
  const unsigned short* ae = (const unsigned short*)&av;
  float v[8];
#pragma unroll
  for (int j = 0; j < 8; ++j) v[j] = bf2f(ae[j]);
  float s = 0.f, s2 = 0.f;
#pragma unroll
  for (int j = 0; j < 8; ++j) { s += v[j]; s2 += v[j] * v[j]; }
#pragma unroll
  for (int m = 1; m < 64; m <<= 1) { s += __shfl_xor(s, m); s2 += __shfl_xor(s2, m); }
  float mean = s * (1.0f / 512.0f);
  float var = s2 * (1.0f / 512.0f) - mean * mean;
  float rstd = rsqrtf(var + 1e-6f);
  uint4 ub = *(const uint4*)(mm + (size_t)row * 2048 + lane * 8);
  const unsigned short* us = (const unsigned short*)&ub;
  unsigned short o[8];
#pragma unroll
  for (int j = 0; j < 8; ++j) o[j] = f2bf((v[j] - mean) * rstd * bf2f(us[j]));
  *(uint4*)(oin + (size_t)row * 512 + lane * 8) = *(uint4*)o;
}

// ---------- MFMA GEMM, 128x128 tile, BK=64, Bt is (N,K) row-major ----------
template <int MODE>
__global__ __launch_bounds__(256) void k_gemm_bt(const unsigned short* __restrict__ A,
                                                 const unsigned short* __restrict__ Bt,
                                                 void* __restrict__ Cout,
                                                 const float* __restrict__ bias,
                                                 const float* __restrict__ xres,
                                                 int M, int Nn, int K, int ntn) {
  __shared__ __align__(16) char lds[32768];
  char* ldsA = lds;
  char* ldsB = lds + 16384;
  int bid = blockIdx.x;
  int mt = bid / ntn, nt = bid - mt * ntn;
  int m0 = mt * 128, n0 = nt * 128;
  int tid = threadIdx.x, lane = tid & 63, wid = tid >> 6;
  int wm = wid >> 1, wn = wid & 1;
  int fr = lane & 15, fq = lane >> 4;
  f32x4 acc[4][4] = {};
  int nK = K >> 6;
  int lco = (lane & 7) * 16;
  int lrow8 = lane >> 3;
  for (int kt = 0; kt < nK; ++kt) {
    int k0 = kt << 6;
#pragma unroll
    for (int p = 0; p < 4; ++p) {
      int chunk = wid * 4 + p;
      int row = chunk * 8 + lrow8;
      int colb = lco ^ ((row & 7) << 4);
      int ar = m0 + row; if (ar >= M) ar = M - 1;
      gload_lds16((const char*)(A + (size_t)ar * K + k0) + colb, ldsA + chunk * 1024);
      gload_lds16((const char*)(Bt + (size_t)(n0 + row) * K + k0) + colb, ldsB + chunk * 1024);
    }
    __syncthreads();
    bf16x8 af[4][2], bfr[4][2];
#pragma unroll
    for (int mi = 0; mi < 4; ++mi) {
      int r = wm * 64 + mi * 16 + fr;
#pragma unroll
      for (int kk = 0; kk < 2; ++kk)
        af[mi][kk] = *(const bf16x8*)(ldsA + swz128(r * 128 + kk * 64 + fq * 16));
    }
#pragma unroll
    for (int ni = 0; ni < 4; ++ni) {
      int r = wn * 64 + ni * 16 + fr;
#pragma unroll
      for (int kk = 0; kk < 2; ++kk)
        bfr[ni][kk] = *(const bf16x8*)(ldsB + swz128(r * 128 + kk * 64 + fq * 16));
    }
#pragma unroll
    for (int mi = 0; mi < 4; ++mi)
#pragma unroll
      for (int ni = 0; ni < 4; ++ni) {
        acc[mi][ni] = MFMA16x16(af[mi][0], bfr[ni][0], acc[mi][ni]);
        acc[mi][ni] = MFMA16x16(af[mi][1], bfr[ni][1], acc[mi][ni]);
      }
    __syncthreads();
  }
#pragma unroll
  for (int mi = 0; mi < 4; ++mi) {
#pragma unroll
    for (int j = 0; j < 4; ++j) {
      int r = m0 + wm * 64 + mi * 16 + fq * 4 + j;
      if (r >= M) continue;
#pragma unroll
      for (int ni = 0; ni < 4; ++ni) {
        int c = n0 + wn * 64 + ni * 16 + fr;
        float v = acc[mi][ni][j];
        if (MODE == 0) {
          ((unsigned short*)Cout)[(size_t)r * Nn + c] = f2bf(silu_f(v));
        } else {
          ((float*)Cout)[(size_t)r * Nn + c] = v + bias[c] + xres[(size_t)r * 512 + c];
        }
      }
    }
  }
}

// ---------- K compact + V^T prestage per (b,h) ----------
// kC[bh][s][64] bf16 (contiguous 128B rows), vT[bh][d=64][ns] bf16; both zero-padded to 64.
__global__ __launch_bounds__(256) void k_kv(const unsigned short* __restrict__ mm,
                                            const int* __restrict__ offs,
                                            unsigned short* __restrict__ kC,
                                            unsigned short* __restrict__ vT, int ns) {
  int bh = blockIdx.x; int b = bh >> 3, h = bh & 7;
  int off = offs[b], len = offs[b + 1] - offs[b];
  int tid = threadIdx.x;
  int npad = (len + 63) & ~63;
  const unsigned short* kp = mm + (size_t)off * 2048 + 1536 + h * 64;
  unsigned short* kc = kC + (size_t)bh * ns * 64;
  for (int i = tid; i < npad * 8; i += 256) {  // K compact copy, 16B per thread
    int row = i >> 3, c8 = (i & 7) * 8;
    uint4 v = {0u, 0u, 0u, 0u};
    if (row < len) v = *(const uint4*)(kp + (size_t)row * 2048 + c8);
    *(uint4*)(kc + row * 64 + c8) = v;
  }
  int lane = tid & 63, w = tid >> 6;
  const unsigned short* vp = mm + (size_t)off * 2048 + 512 + h * 64 + lane;
  unsigned short* vt = vT + ((size_t)bh * 64 + lane) * ns;
  for (int c = w; c < (npad >> 3); c += 4) {  // V^T: lane=d, walk s in 8s
    int s8 = c << 3;
    unsigned short r[8];
#pragma unroll
    for (int j = 0; j < 8; ++j)
      r[j] = (s8 + j < len) ? vp[(size_t)(s8 + j) * 2048] : (unsigned short)0;
    *(uint4*)(vt + s8) = *(uint4*)r;
  }
}

// ---------- jagged causal SiLU-attention, v3: flat balanced wave units ----------
// wave unit = (b,qt32,h) from desc-sorted tile list; no barriers; K from kC, V from vT.
__global__ __launch_bounds__(256) void k_attn3(const unsigned short* __restrict__ mm,
                                               const unsigned short* __restrict__ kC,
                                               const unsigned short* __restrict__ vT,
                                               const int* __restrict__ offs,
                                               const int* __restrict__ tiles,
                                               unsigned short* __restrict__ attnb,
                                               float inv_n, int ns) {
  __shared__ __align__(16) char sP[16384];  // 4KB per wave: P [32 q][64 s] bf16, swz128
  int tid = threadIdx.x, lane = tid & 63, wid = tid >> 6;
  int w = blockIdx.x * 4 + wid;
  if (w >= tiles[0]) return;  // wave-uniform exit (no barriers in kernel)
  int e = tiles[1 + (w >> 3)];
  int h = w & 7;
  int b = e >> 16, qt = e & 0xffff;
  int bh = b * 8 + h;
  int off = offs[b], len = offs[b + 1] - offs[b];
  int qb = qt * 32;
  int fr = lane & 15, fq = lane >> 4;
  const unsigned short* qp = mm + (size_t)off * 2048 + 1024 + h * 64;
  const unsigned short* kcp = kC + (size_t)bh * ns * 64;
  const unsigned short* vtp = vT + (size_t)bh * 64 * ns;
  bf16x8 aq[2][2];  // Q frags: row q = mi*16+fr, k = kk*32+fq*8+j
#pragma unroll
  for (int mi = 0; mi < 2; ++mi) {
    int qr = qb + mi * 16 + fr; if (qr >= len) qr = len - 1;
#pragma unroll
    for (int kk = 0; kk < 2; ++kk)
      aq[mi][kk] = *(const bf16x8*)(qp + (size_t)qr * 2048 + kk * 32 + fq * 8);
  }
  f32x4 accO[2][4] = {};
  char* pw = sP + wid * 4096;
  int nkt = (qb >> 6) + 1;
  for (int kt = 0; kt < nkt; ++kt) {
    int s0 = kt << 6;
    // QK^T: K frags from compact kC (contiguous 2KB per frag-pair)
    f32x4 sacc[2][4] = {};
#pragma unroll
    for (int ni = 0; ni < 4; ++ni) {
      const unsigned short* kr = kcp + (size_t)(s0 + ni * 16 + fr) * 64 + fq * 8;
      bf16x8 k0 = *(const bf16x8*)kr;
      bf16x8 k1 = *(const bf16x8*)(kr + 32);
#pragma unroll
      for (int mi = 0; mi < 2; ++mi) {
        sacc[mi][ni] = MFMA16x16(aq[mi][0], k0, sacc[mi][ni]);
        sacc[mi][ni] = MFMA16x16(aq[mi][1], k1, sacc[mi][ni]);
      }
    }
    // V^T frags: issue loads early (independent) so P round-trip hides them
    bf16x8 vf[4][2];
#pragma unroll
    for (int nd = 0; nd < 4; ++nd)
#pragma unroll
      for (int kk = 0; kk < 2; ++kk)
        vf[nd][kk] = *(const bf16x8*)(vtp + (size_t)(nd * 16 + fr) * ns + s0 + kk * 32 + fq * 8);
    // silu/n + causal mask -> P (wave-private LDS)
#pragma unroll
    for (int mi = 0; mi < 2; ++mi)
#pragma unroll
      for (int ni = 0; ni < 4; ++ni)
#pragma unroll
        for (int j = 0; j < 4; ++j) {
          int pq = qb + mi * 16 + fq * 4 + j;
          int ps = s0 + ni * 16 + fr;
          float v = (ps <= pq) ? silu_f(sacc[mi][ni][j]) * inv_n : 0.0f;
          *(unsigned short*)(pw + swz128((mi * 16 + fq * 4 + j) * 128 + (ni * 16 + fr) * 2)) =
              f2bf(v);
        }
    bf16x8 pa[2][2];
#pragma unroll
    for (int mi = 0; mi < 2; ++mi) {
      pa[mi][0] = *(const bf16x8*)(pw + swz128((mi * 16 + fr) * 128 + fq * 16));
      pa[mi][1] = *(const bf16x8*)(pw + swz128((mi * 16 + fr) * 128 + 64 + fq * 16));
    }
#pragma unroll
    for (int nd = 0; nd < 4; ++nd)
#pragma unroll
      for (int mi = 0; mi < 2; ++mi) {
        accO[mi][nd] = MFMA16x16(pa[mi][0], vf[nd][0], accO[mi][nd]);
        accO[mi][nd] = MFMA16x16(pa[mi][1], vf[nd][1], accO[mi][nd]);
      }
  }
#pragma unroll
  for (int mi = 0; mi < 2; ++mi)
#pragma unroll
    for (int nd = 0; nd < 4; ++nd)
#pragma unroll
      for (int j = 0; j < 4; ++j) {
        int pq = qb + mi * 16 + fq * 4 + j;
        if (pq < len)
          attnb[(size_t)(off + pq) * 512 + h * 64 + nd * 16 + fr] = f2bf(accO[mi][nd][j]);
      }
}

extern "C" void kernel_launch(void* const* d_in, const int* in_sizes, int n_in,
                              void* d_out, int out_size, void* d_ws, size_t ws_size,
                              hipStream_t stream) {
  const float* x = (const float*)d_in[0];
  const int* xoff = (const int*)d_in[1];
  const float* uvqk = (const float*)d_in[3];
  const float* ow = (const float*)d_in[4];
  const float* obias = (const float*)d_in[5];

  const int D = 512;
  int T = in_sizes[0] / D;
  int B = in_sizes[1] - 1;
  int nm = 1;
  while ((long long)nm * nm < (long long)in_sizes[2]) nm <<= 1;  // mask dim (1024)
  int qtmax = nm / 32;

  char* w = (char*)d_ws;
  size_t p = 0;
  auto alloc = [&](size_t bytes) { size_t r = p; p += (bytes + 255) & ~(size_t)255; return r; };
  int* offs = (int*)(w + alloc(sizeof(int) * (size_t)(B + 1)));
  int* tiles = (int*)(w + alloc(sizeof(int) * (size_t)(1 + B * qtmax)));
  unsigned short* normed = (unsigned short*)(w + alloc((size_t)T * 512 * 2));
  unsigned short* mm = (unsigned short*)(w + alloc((size_t)T * 2048 * 2));
  unsigned short* attnb = (unsigned short*)(w + alloc((size_t)T * 512 * 2));
  unsigned short* oin = (unsigned short*)(w + alloc((size_t)T * 512 * 2));
  unsigned short* uvqkT = (unsigned short*)(w + alloc((size_t)2048 * 512 * 2));
  unsigned short* owb = (unsigned short*)(w + alloc((size_t)512 * 512 * 2));
  unsigned short* vT = (unsigned short*)(w + alloc((size_t)B * 8 * 64 * (size_t)nm * 2));
  unsigned short* kC = (unsigned short*)(w + alloc((size_t)B * 8 * (size_t)nm * 64 * 2));

  k_prep<<<1, 256, 0, stream>>>(xoff, B + 1, offs, tiles, qtmax);
  k_conv_uvqkT<<<dim3(64, 16), 256, 0, stream>>>(uvqk, uvqkT);
  k_conv_bf16<<<1024, 256, 0, stream>>>(ow, owb, 512 * 512);
  k_ln_x<<<(T + 3) / 4, 256, 0, stream>>>(x, normed, T);
  int ntm = (T + 127) / 128;
  k_gemm_bt<0><<<ntm * 16, 256, 0, stream>>>(normed, uvqkT, (void*)mm, nullptr, nullptr,
                                             T, 2048, 512, 16);
  k_kv<<<B * 8, 256, 0, stream>>>(mm, offs, kC, vT, nm);
  int maxw = B * qtmax * 8;
  k_attn3<<<(maxw + 3) / 4, 256, 0, stream>>>(mm, kC, vT, offs, tiles, attnb,
                                              1.0f / (float)nm, nm);
  k_ln_mul_u<<<(T + 3) / 4, 256, 0, stream>>>(attnb, mm, oin, T);
  k_gemm_bt<1><<<ntm * 4, 256, 0, stream>>>(oin, owb, d_out, obias, x, T, 512, 512, 4);
}

// Round 4
// 223.552 us; speedup vs baseline: 1.3140x; 1.3140x over previous
//
#include <hip/hip_runtime.h>
#include <hip/hip_bf16.h>
#include <math.h>

typedef short bf16x8 __attribute__((ext_vector_type(8)));
typedef float f32x4 __attribute__((ext_vector_type(4)));

#define MFMA16x16(a, b, c) __builtin_amdgcn_mfma_f32_16x16x32_bf16(a, b, c, 0, 0, 0)

__device__ __forceinline__ float silu_f(float v) { return v / (1.0f + __expf(-v)); }
// XOR swizzle for [row][128B] LDS tiles
__device__ __forceinline__ int swz128(int b) { return b ^ (((b >> 7) & 7) << 4); }

__device__ __forceinline__ unsigned short f2bf(float f) {  // RNE f32->bf16
  union { float f; unsigned u; } x; x.f = f;
  unsigned r = x.u + 0x7fffu + ((x.u >> 16) & 1u);
  return (unsigned short)(r >> 16);
}
__device__ __forceinline__ float bf2f(unsigned short h) {
  union { unsigned u; float f; } x; x.u = ((unsigned)h) << 16;
  return x.f;
}

__device__ __forceinline__ void gload_lds16(const void* g, void* l) {
  __builtin_amdgcn_global_load_lds((__attribute__((address_space(1))) unsigned int*)g,
                                   (__attribute__((address_space(3))) unsigned int*)l,
                                   16, 0, 0);
}

// ---------- offsets decode + balanced tile list (desc by work), PARALLEL ----------
// position of valid (b,qt) = base[qt] + rank_b, base[qt] = sum_{qt'>qt} cnt[qt'],
// rank_b = #{b'<b valid at qt}. All O(B) loops, no serial global chain.
__global__ void k_prep(const int* __restrict__ raw, int Bp1, int* __restrict__ offs,
                       int* __restrict__ tiles, int qtmax) {
  __shared__ int s_off[128], s_nt[128], s_cnt[128], s_base[128];
  int t = threadIdx.x;
  int B = Bp1 - 1;
  bool is64 = (raw[3] == 0);
  if (t < Bp1) { int v = is64 ? raw[2 * t] : raw[t]; offs[t] = v; s_off[t] = v; }
  __syncthreads();
  if (t < B) s_nt[t] = (s_off[t + 1] - s_off[t] + 31) >> 5;
  __syncthreads();
  if (t < qtmax) {
    int c = 0;
    for (int b = 0; b < B; ++b) c += (t < s_nt[b]) ? 1 : 0;
    s_cnt[t] = c;
  }
  __syncthreads();
  if (t < qtmax) {
    int basev = 0;
    for (int q2 = t + 1; q2 < qtmax; ++q2) basev += s_cnt[q2];
    s_base[t] = basev;
  }
  __syncthreads();
  if (t == 0) tiles[0] = (s_base[0] + s_cnt[0]) * 8;  // total wave units (x8 heads)
  for (int i = t; i < qtmax * B; i += 256) {
    int qt = i / B, b = i - qt * B;
    if (qt < s_nt[b]) {
      int rank = 0;
      for (int b2 = 0; b2 < b; ++b2) rank += (qt < s_nt[b2]) ? 1 : 0;
      tiles[1 + s_base[qt] + rank] = (b << 16) | qt;
    }
  }
}

// ---------- uvqk (512x2048 f32) -> uvqkT (2048x512 bf16), transposed ----------
__global__ __launch_bounds__(256) void k_conv_uvqkT(const float* __restrict__ uvqk,
                                                    unsigned short* __restrict__ uvqkT) {
  __shared__ float tile[32][33];
  int n0 = blockIdx.x * 32, k0 = blockIdx.y * 32;
  int tx = threadIdx.x & 31;
  int ty = threadIdx.x >> 5;
#pragma unroll
  for (int i = 0; i < 4; ++i)
    tile[ty + 8 * i][tx] = uvqk[(size_t)(k0 + ty + 8 * i) * 2048 + n0 + tx];
  __syncthreads();
#pragma unroll
  for (int i = 0; i < 4; ++i) {
    int nn = ty + 8 * i;
    uvqkT[(size_t)(n0 + nn) * 512 + k0 + tx] = f2bf(tile[tx][nn]);
  }
}

__global__ __launch_bounds__(256) void k_conv_bf16(const float* __restrict__ in,
                                                   unsigned short* __restrict__ out, int n) {
  int i = blockIdx.x * 256 + threadIdx.x;
  if (i < n) out[i] = f2bf(in[i]);
}

// ---------- LayerNorm(x) -> bf16, one wave per 512-row ----------
__global__ __launch_bounds__(256) void k_ln_x(const float* __restrict__ x,
                                              unsigned short* __restrict__ normed, int T) {
  int lane = threadIdx.x & 63, wid = threadIdx.x >> 6;
  int row = blockIdx.x * 4 + wid;
  if (row >= T) return;
  const float4* xr = (const float4*)(x + (size_t)row * 512);
  float4 a = xr[lane * 2], b = xr[lane * 2 + 1];
  float s = a.x + a.y + a.z + a.w + b.x + b.y + b.z + b.w;
  float s2 = a.x * a.x + a.y * a.y + a.z * a.z + a.w * a.w +
             b.x * b.x + b.y * b.y + b.z * b.z + b.w * b.w;
#pragma unroll
  for (int m = 1; m < 64; m <<= 1) { s += __shfl_xor(s, m); s2 += __shfl_xor(s2, m); }
  float mean = s * (1.0f / 512.0f);
  float var = s2 * (1.0f / 512.0f) - mean * mean;
  float rstd = rsqrtf(var + 1e-6f);
  float v[8] = {a.x, a.y, a.z, a.w, b.x, b.y, b.z, b.w};
  unsigned short o[8];
#pragma unroll
  for (int j = 0; j < 8; ++j) o[j] = f2bf((v[j] - mean) * rstd);
  *(uint4*)(normed + (size_t)row * 512 + lane * 8) = *(uint4*)o;
}

// ---------- o_input = u * LayerNorm(attn_bf16) -> bf16 ----------
__global__ __launch_bounds__(256) void k_ln_mul_u(const unsigned short* __restrict__ attnb,
                                                  const unsigned short* __restrict__ mm,
                                                  unsigned short* __restrict__ oin, int T) {
  int lane = threadIdx.x & 63, wid = threadIdx.x >> 6;
  int row = blockIdx.x * 4 + wid;
  if (row >= T) return;
  uint4 av = *(const uint4*)(attnb + (size_t)row * 512 + lane * 8);
  const unsigned short* ae = (const unsigned short*)&av;
  float v[8];
#pragma unroll
  for (int j = 0; j < 8; ++j) v[j] = bf2f(ae[j]);
  float s = 0.f, s2 = 0.f;
#pragma unroll
  for (int j = 0; j < 8; ++j) { s += v[j]; s2 += v[j] * v[j]; }
#pragma unroll
  for (int m = 1; m < 64; m <<= 1) { s += __shfl_xor(s, m); s2 += __shfl_xor(s2, m); }
  float mean = s * (1.0f / 512.0f);
  float var = s2 * (1.0f / 512.0f) - mean * mean;
  float rstd = rsqrtf(var + 1e-6f);
  uint4 ub = *(const uint4*)(mm + (size_t)row * 2048 + lane * 8);
  const unsigned short* us = (const unsigned short*)&ub;
  unsigned short o[8];
#pragma unroll
  for (int j = 0; j < 8; ++j) o[j] = f2bf((v[j] - mean) * rstd * bf2f(us[j]));
  *(uint4*)(oin + (size_t)row * 512 + lane * 8) = *(uint4*)o;
}

// ---------- MFMA GEMM, 128x128 tile, BK=64, Bt is (N,K) row-major ----------
template <int MODE>
__global__ __launch_bounds__(256) void k_gemm_bt(const unsigned short* __restrict__ A,
                                                 const unsigned short* __restrict__ Bt,
                                                 void* __restrict__ Cout,
                                                 const float* __restrict__ bias,
                                                 const float* __restrict__ xres,
                                                 int M, int Nn, int K, int ntn) {
  __shared__ __align__(16) char lds[32768];
  char* ldsA = lds;
  char* ldsB = lds + 16384;
  int bid = blockIdx.x;
  int mt = bid / ntn, nt = bid - mt * ntn;
  int m0 = mt * 128, n0 = nt * 128;
  int tid = threadIdx.x, lane = tid & 63, wid = tid >> 6;
  int wm = wid >> 1, wn = wid & 1;
  int fr = lane & 15, fq = lane >> 4;
  f32x4 acc[4][4] = {};
  int nK = K >> 6;
  int lco = (lane & 7) * 16;
  int lrow8 = lane >> 3;
  for (int kt = 0; kt < nK; ++kt) {
    int k0 = kt << 6;
#pragma unroll
    for (int p = 0; p < 4; ++p) {
      int chunk = wid * 4 + p;
      int row = chunk * 8 + lrow8;
      int colb = lco ^ ((row & 7) << 4);
      int ar = m0 + row; if (ar >= M) ar = M - 1;
      gload_lds16((const char*)(A + (size_t)ar * K + k0) + colb, ldsA + chunk * 1024);
      gload_lds16((const char*)(Bt + (size_t)(n0 + row) * K + k0) + colb, ldsB + chunk * 1024);
    }
    __syncthreads();
    bf16x8 af[4][2], bfr[4][2];
#pragma unroll
    for (int mi = 0; mi < 4; ++mi) {
      int r = wm * 64 + mi * 16 + fr;
#pragma unroll
      for (int kk = 0; kk < 2; ++kk)
        af[mi][kk] = *(const bf16x8*)(ldsA + swz128(r * 128 + kk * 64 + fq * 16));
    }
#pragma unroll
    for (int ni = 0; ni < 4; ++ni) {
      int r = wn * 64 + ni * 16 + fr;
#pragma unroll
      for (int kk = 0; kk < 2; ++kk)
        bfr[ni][kk] = *(const bf16x8*)(ldsB + swz128(r * 128 + kk * 64 + fq * 16));
    }
#pragma unroll
    for (int mi = 0; mi < 4; ++mi)
#pragma unroll
      for (int ni = 0; ni < 4; ++ni) {
        acc[mi][ni] = MFMA16x16(af[mi][0], bfr[ni][0], acc[mi][ni]);
        acc[mi][ni] = MFMA16x16(af[mi][1], bfr[ni][1], acc[mi][ni]);
      }
    __syncthreads();
  }
#pragma unroll
  for (int mi = 0; mi < 4; ++mi) {
#pragma unroll
    for (int j = 0; j < 4; ++j) {
      int r = m0 + wm * 64 + mi * 16 + fq * 4 + j;
      if (r >= M) continue;
#pragma unroll
      for (int ni = 0; ni < 4; ++ni) {
        int c = n0 + wn * 64 + ni * 16 + fr;
        float v = acc[mi][ni][j];
        if (MODE == 0) {
          ((unsigned short*)Cout)[(size_t)r * Nn + c] = f2bf(silu_f(v));
        } else {
          ((float*)Cout)[(size_t)r * Nn + c] = v + bias[c] + xres[(size_t)r * 512 + c];
        }
      }
    }
  }
}

// ---------- K compact + V^T prestage per (b,h) ----------
__global__ __launch_bounds__(256) void k_kv(const unsigned short* __restrict__ mm,
                                            const int* __restrict__ offs,
                                            unsigned short* __restrict__ kC,
                                            unsigned short* __restrict__ vT, int ns) {
  int bh = blockIdx.x; int b = bh >> 3, h = bh & 7;
  int off = offs[b], len = offs[b + 1] - offs[b];
  int tid = threadIdx.x;
  int npad = (len + 63) & ~63;
  const unsigned short* kp = mm + (size_t)off * 2048 + 1536 + h * 64;
  unsigned short* kc = kC + (size_t)bh * ns * 64;
  for (int i = tid; i < npad * 8; i += 256) {  // K compact copy, 16B per thread
    int row = i >> 3, c8 = (i & 7) * 8;
    uint4 v = {0u, 0u, 0u, 0u};
    if (row < len) v = *(const uint4*)(kp + (size_t)row * 2048 + c8);
    *(uint4*)(kc + row * 64 + c8) = v;
  }
  int lane = tid & 63, w = tid >> 6;
  const unsigned short* vp = mm + (size_t)off * 2048 + 512 + h * 64 + lane;
  unsigned short* vt = vT + ((size_t)bh * 64 + lane) * ns;
  for (int c = w; c < (npad >> 3); c += 4) {  // V^T: lane=d, walk s in 8s
    int s8 = c << 3;
    unsigned short r[8];
#pragma unroll
    for (int j = 0; j < 8; ++j)
      r[j] = (s8 + j < len) ? vp[(size_t)(s8 + j) * 2048] : (unsigned short)0;
    *(uint4*)(vt + s8) = *(uint4*)r;
  }
}

// ---------- jagged causal SiLU-attention, v3: flat balanced wave units ----------
__global__ __launch_bounds__(256) void k_attn3(const unsigned short* __restrict__ mm,
                                               const unsigned short* __restrict__ kC,
                                               const unsigned short* __restrict__ vT,
                                               const int* __restrict__ offs,
                                               const int* __restrict__ tiles,
                                               unsigned short* __restrict__ attnb,
                                               float inv_n, int ns) {
  __shared__ __align__(16) char sP[16384];  // 4KB per wave: P [32 q][64 s] bf16, swz128
  int tid = threadIdx.x, lane = tid & 63, wid = tid >> 6;
  int w = blockIdx.x * 4 + wid;
  if (w >= tiles[0]) return;  // wave-uniform exit (no barriers in kernel)
  int e = tiles[1 + (w >> 3)];
  int h = w & 7;
  int b = e >> 16, qt = e & 0xffff;
  int bh = b * 8 + h;
  int off = offs[b], len = offs[b + 1] - offs[b];
  int qb = qt * 32;
  int fr = lane & 15, fq = lane >> 4;
  const unsigned short* qp = mm + (size_t)off * 2048 + 1024 + h * 64;
  const unsigned short* kcp = kC + (size_t)bh * ns * 64;
  const unsigned short* vtp = vT + (size_t)bh * 64 * ns;
  bf16x8 aq[2][2];  // Q frags: row q = mi*16+fr, k = kk*32+fq*8+j
#pragma unroll
  for (int mi = 0; mi < 2; ++mi) {
    int qr = qb + mi * 16 + fr; if (qr >= len) qr = len - 1;
#pragma unroll
    for (int kk = 0; kk < 2; ++kk)
      aq[mi][kk] = *(const bf16x8*)(qp + (size_t)qr * 2048 + kk * 32 + fq * 8);
  }
  f32x4 accO[2][4] = {};
  char* pw = sP + wid * 4096;
  int nkt = (qb >> 6) + 1;
  for (int kt = 0; kt < nkt; ++kt) {
    int s0 = kt << 6;
    // QK^T: K frags from compact kC (contiguous 2KB per frag-pair)
    f32x4 sacc[2][4] = {};
#pragma unroll
    for (int ni = 0; ni < 4; ++ni) {
      const unsigned short* kr = kcp + (size_t)(s0 + ni * 16 + fr) * 64 + fq * 8;
      bf16x8 k0 = *(const bf16x8*)kr;
      bf16x8 k1 = *(const bf16x8*)(kr + 32);
#pragma unroll
      for (int mi = 0; mi < 2; ++mi) {
        sacc[mi][ni] = MFMA16x16(aq[mi][0], k0, sacc[mi][ni]);
        sacc[mi][ni] = MFMA16x16(aq[mi][1], k1, sacc[mi][ni]);
      }
    }
    // V^T frags: issue loads early (independent) so P round-trip hides them
    bf16x8 vf[4][2];
#pragma unroll
    for (int nd = 0; nd < 4; ++nd)
#pragma unroll
      for (int kk = 0; kk < 2; ++kk)
        vf[nd][kk] = *(const bf16x8*)(vtp + (size_t)(nd * 16 + fr) * ns + s0 + kk * 32 + fq * 8);
    // silu/n + causal mask -> P (wave-private LDS)
#pragma unroll
    for (int mi = 0; mi < 2; ++mi)
#pragma unroll
      for (int ni = 0; ni < 4; ++ni)
#pragma unroll
        for (int j = 0; j < 4; ++j) {
          int pq = qb + mi * 16 + fq * 4 + j;
          int ps = s0 + ni * 16 + fr;
          float v = (ps <= pq) ? silu_f(sacc[mi][ni][j]) * inv_n : 0.0f;
          *(unsigned short*)(pw + swz128((mi * 16 + fq * 4 + j) * 128 + (ni * 16 + fr) * 2)) =
              f2bf(v);
        }
    bf16x8 pa[2][2];
#pragma unroll
    for (int mi = 0; mi < 2; ++mi) {
      pa[mi][0] = *(const bf16x8*)(pw + swz128((mi * 16 + fr) * 128 + fq * 16));
      pa[mi][1] = *(const bf16x8*)(pw + swz128((mi * 16 + fr) * 128 + 64 + fq * 16));
    }
#pragma unroll
    for (int nd = 0; nd < 4; ++nd)
#pragma unroll
      for (int mi = 0; mi < 2; ++mi) {
        accO[mi][nd] = MFMA16x16(pa[mi][0], vf[nd][0], accO[mi][nd]);
        accO[mi][nd] = MFMA16x16(pa[mi][1], vf[nd][1], accO[mi][nd]);
      }
  }
#pragma unroll
  for (int mi = 0; mi < 2; ++mi)
#pragma unroll
    for (int nd = 0; nd < 4; ++nd)
#pragma unroll
      for (int j = 0; j < 4; ++j) {
        int pq = qb + mi * 16 + fq * 4 + j;
        if (pq < len)
          attnb[(size_t)(off + pq) * 512 + h * 64 + nd * 16 + fr] = f2bf(accO[mi][nd][j]);
      }
}

extern "C" void kernel_launch(void* const* d_in, const int* in_sizes, int n_in,
                              void* d_out, int out_size, void* d_ws, size_t ws_size,
                              hipStream_t stream) {
  const float* x = (const float*)d_in[0];
  const int* xoff = (const int*)d_in[1];
  const float* uvqk = (const float*)d_in[3];
  const float* ow = (const float*)d_in[4];
  const float* obias = (const float*)d_in[5];

  const int D = 512;
  int T = in_sizes[0] / D;
  int B = in_sizes[1] - 1;
  int nm = 1;
  while ((long long)nm * nm < (long long)in_sizes[2]) nm <<= 1;  // mask dim (1024)
  int qtmax = nm / 32;

  char* w = (char*)d_ws;
  size_t p = 0;
  auto alloc = [&](size_t bytes) { size_t r = p; p += (bytes + 255) & ~(size_t)255; return r; };
  int* offs = (int*)(w + alloc(sizeof(int) * (size_t)(B + 1)));
  int* tiles = (int*)(w + alloc(sizeof(int) * (size_t)(1 + B * qtmax)));
  unsigned short* normed = (unsigned short*)(w + alloc((size_t)T * 512 * 2));
  unsigned short* mm = (unsigned short*)(w + alloc((size_t)T * 2048 * 2));
  unsigned short* attnb = (unsigned short*)(w + alloc((size_t)T * 512 * 2));
  unsigned short* oin = (unsigned short*)(w + alloc((size_t)T * 512 * 2));
  unsigned short* uvqkT = (unsigned short*)(w + alloc((size_t)2048 * 512 * 2));
  unsigned short* owb = (unsigned short*)(w + alloc((size_t)512 * 512 * 2));
  unsigned short* vT = (unsigned short*)(w + alloc((size_t)B * 8 * 64 * (size_t)nm * 2));
  unsigned short* kC = (unsigned short*)(w + alloc((size_t)B * 8 * (size_t)nm * 64 * 2));

  k_prep<<<1, 256, 0, stream>>>(xoff, B + 1, offs, tiles, qtmax);
  k_conv_uvqkT<<<dim3(64, 16), 256, 0, stream>>>(uvqk, uvqkT);
  k_conv_bf16<<<1024, 256, 0, stream>>>(ow, owb, 512 * 512);
  k_ln_x<<<(T + 3) / 4, 256, 0, stream>>>(x, normed, T);
  int ntm = (T + 127) / 128;
  k_gemm_bt<0><<<ntm * 16, 256, 0, stream>>>(normed, uvqkT, (void*)mm, nullptr, nullptr,
                                             T, 2048, 512, 16);
  k_kv<<<B * 8, 256, 0, stream>>>(mm, offs, kC, vT, nm);
  int maxw = B * qtmax * 8;
  k_attn3<<<(maxw + 3) / 4, 256, 0, stream>>>(mm, kC, vT, offs, tiles, attnb,
                                              1.0f / (float)nm, nm);
  k_ln_mul_u<<<(T + 3) / 4, 256, 0, stream>>>(attnb, mm, oin, T);
  k_gemm_bt<1><<<ntm * 4, 256, 0, stream>>>(oin, owb, d_out, obias, x, T, 512, 512, 4);
}